// Round 11
// baseline (297.958 us; speedup 1.0000x reference)
//
#include <hip/hip_runtime.h>
#include <math.h>

// Problem constants
#define Bq 2
#define Sq 2048
#define Cq 768
#define Hq 12
#define Dq 64

#define PANEL_SHORTS 196608   // 24 steps x 8192 shorts (128 rows x [hi32|lo32])
#define PANELS_X  32
#define PANELS_WQ 18
#define PANELS_WP 6

typedef __bf16 bfv8 __attribute__((ext_vector_type(8)));
typedef float f32x4 __attribute__((ext_vector_type(4)));
#define MFMA16(a, b, c) __builtin_amdgcn_mfma_f32_16x16x32_bf16(a, b, c, 0, 0, 0)

static __device__ inline unsigned short bfbits(float x) {
    __bf16 b = (__bf16)x;
    return __builtin_bit_cast(unsigned short, b);
}
static __device__ inline float bf2f(unsigned short b) {
    return (float)__builtin_bit_cast(__bf16, b);
}
static __device__ inline unsigned short lobits(float x, unsigned short hb) {
    return bfbits(x - bf2f(hb));
}

// async 16B global->LDS copy; lds dest is wave-uniform base (+lane*16 by HW)
static __device__ inline void gld_lds16(const unsigned short* g, unsigned short* l) {
    __builtin_amdgcn_global_load_lds(
        (const __attribute__((address_space(1))) unsigned int*)g,
        (__attribute__((address_space(3))) unsigned int*)l, 16, 0, 0);
}

// DPP butterfly reductions over 16 lanes (VALU pipe, no LDS traffic).
template <int CTRL>
static __device__ inline float dppmax(float x) {
    int y = __builtin_amdgcn_mov_dpp(__builtin_bit_cast(int, x), CTRL, 0xF, 0xF, true);
    return fmaxf(x, __builtin_bit_cast(float, y));
}
template <int CTRL>
static __device__ inline float dppadd(float x) {
    int y = __builtin_amdgcn_mov_dpp(__builtin_bit_cast(int, x), CTRL, 0xF, 0xF, true);
    return x + __builtin_bit_cast(float, y);
}
static __device__ inline float redmax16(float x) {
    x = dppmax<0xB1>(x); x = dppmax<0x4E>(x);
    x = dppmax<0x141>(x); x = dppmax<0x140>(x);
    return x;
}
static __device__ inline float redsum16(float x) {
    x = dppadd<0xB1>(x); x = dppadd<0x4E>(x);
    x = dppadd<0x141>(x); x = dppadd<0x140>(x);
    return x;
}

// ---------------------------------------------------------------------------
// Kernel 0: RoPE cos/sin tables  [S][32] each, fp64-accurate
// ---------------------------------------------------------------------------
__global__ void freq_kernel(float* __restrict__ ctab, float* __restrict__ stab) {
    int idx = blockIdx.x * blockDim.x + threadIdx.x;   // 0..65535
    int s = idx >> 5;
    int i = idx & 31;
    double f = (double)s * exp(-(double)i * 0.28782313662425573); // ln(1e4)/32
    ctab[idx] = (float)cos(f);
    stab[idx] = (float)sin(f);
}

// ---------------------------------------------------------------------------
// Kernel 1: fp32 -> bf16 hi/lo split into GEMM panel-blocked, PRE-SWIZZLED
// layout (identity DMA image for the GEMM).
// ---------------------------------------------------------------------------
__global__ __launch_bounds__(256) void split_kernel(
    const float* __restrict__ x, const float* __restrict__ wq,
    const float* __restrict__ wp,
    unsigned short* __restrict__ xs, unsigned short* __restrict__ wqs,
    unsigned short* __restrict__ wps)
{
    const int cid  = blockIdx.x * 256 + threadIdx.x;  // 16B output chunk id
    const int panel = cid / 24576;                    // PANEL_SHORTS/8
    const int pos8  = cid % 24576;
    const int step = pos8 >> 10;
    const int rem  = pos8 & 1023;
    const int J    = rem >> 6;
    const int lane = rem & 63;
    const int rowp = J * 8 + (lane >> 3);
    const int lc   = (lane & 7) ^ (rowp & 7);
    const int k    = step * 32 + (lc & 3) * 8;
    const int islo = lc >> 2;
    const float* src; unsigned short* dst; int prow;
    if (panel < PANELS_X) {
        src = x;  dst = xs;  prow = panel;
    } else if (panel < PANELS_X + PANELS_WQ) {
        src = wq; dst = wqs; prow = panel - PANELS_X;
    } else {
        src = wp; dst = wps; prow = panel - PANELS_X - PANELS_WQ;
    }
    const int row = prow * 128 + rowp;
    float4 v0 = *(const float4*)(src + (size_t)row * Cq + k);
    float4 v1 = *(const float4*)(src + (size_t)row * Cq + k + 4);
    float vf[8] = {v0.x, v0.y, v0.z, v0.w, v1.x, v1.y, v1.z, v1.w};
    unsigned short o[8];
    #pragma unroll
    for (int j = 0; j < 8; ++j) {
        unsigned short h = bfbits(vf[j]);
        o[j] = islo ? lobits(vf[j], h) : h;
    }
    *(uint4*)&dst[(size_t)prow * PANEL_SHORTS + (size_t)pos8 * 8] = *(uint4*)o;
}

// ---------------------------------------------------------------------------
// MFMA NT GEMM on panel-blocked pre-swizzled inputs. 128x128 tile, BK=32,
// 4 waves 2x2, 4x4 acc/wave, 3-term split. Staging = identity global_load_lds.
// MODE 0: QKV + RoPE epilogue. q -> paired [B,H,S,128]; k,v -> attn blocked
//         images. q pre-scaled 1/8.
// MODE 1: proj + bias -> fp32 [M][768].
// ---------------------------------------------------------------------------
template <int MODE>
__global__ __launch_bounds__(256) void gemm_mfma_kernel(
    const unsigned short* __restrict__ Apr, const unsigned short* __restrict__ Bpr,
    const float* __restrict__ ctab, const float* __restrict__ stab,
    unsigned short* __restrict__ qp, unsigned short* __restrict__ kp,
    unsigned short* __restrict__ vp,
    float* __restrict__ out0, const float* __restrict__ bias)
{
    __shared__ unsigned short sA[128 * 64];
    __shared__ unsigned short sB[128 * 64];

    const int t    = threadIdx.x;
    const int w    = t >> 6;
    const int lane = t & 63;
    const int ml   = lane & 15;
    const int quad = lane >> 4;
    const int wm   = w >> 1;
    const int wn   = w & 1;

    const int mBase = blockIdx.y * 128;
    const int nBase = blockIdx.x * 128;

    // staging role: waves 0,1 -> sA; waves 2,3 -> sB; wl picks 8KB half
    const bool isB = (w >= 2);
    const unsigned short* gpan = (isB ? Bpr : Apr)
        + (size_t)((isB ? nBase : mBase) >> 7) * PANEL_SHORTS;
    unsigned short* sdst = isB ? sB : sA;
    const int wl = w & 1;
    const int Jb = wl * 8;

    f32x4 acc[4][4];
    #pragma unroll
    for (int mi = 0; mi < 4; ++mi)
        #pragma unroll
        for (int ni = 0; ni < 4; ++ni)
            acc[mi][ni] = (f32x4){0.f, 0.f, 0.f, 0.f};

    for (int k0 = 0; k0 < Cq; k0 += 32) {
        const unsigned short* gt = gpan + (k0 >> 5) * 8192;
        __syncthreads();
        #pragma unroll
        for (int j = 0; j < 8; ++j)
            gld_lds16(gt + (Jb + j) * 512 + lane * 8, sdst + (Jb + j) * 512);
        __syncthreads();

        bfv8 aFh[4], aFl[4], bFh[4], bFl[4];
        #pragma unroll
        for (int mi = 0; mi < 4; ++mi) {
            const int row = wm * 64 + mi * 16 + ml;
            aFh[mi] = *(const bfv8*)&sA[row * 64 + ((quad ^ (row & 7)) << 3)];
            aFl[mi] = *(const bfv8*)&sA[row * 64 + (((4 + quad) ^ (row & 7)) << 3)];
        }
        #pragma unroll
        for (int ni = 0; ni < 4; ++ni) {
            const int row = wn * 64 + ni * 16 + ml;
            bFh[ni] = *(const bfv8*)&sB[row * 64 + ((quad ^ (row & 7)) << 3)];
            bFl[ni] = *(const bfv8*)&sB[row * 64 + (((4 + quad) ^ (row & 7)) << 3)];
        }
        #pragma unroll
        for (int mi = 0; mi < 4; ++mi)
            #pragma unroll
            for (int ni = 0; ni < 4; ++ni) {
                acc[mi][ni] = MFMA16(aFh[mi], bFh[ni], acc[mi][ni]);
                acc[mi][ni] = MFMA16(aFl[mi], bFh[ni], acc[mi][ni]);
                acc[mi][ni] = MFMA16(aFh[mi], bFl[ni], acc[mi][ni]);
            }
    }

    // ---- epilogue (C-layout: row = quad*4 + r, col = ml) ----
    if (MODE == 0) {
        const int which = nBase / Cq;   // 0=q 1=k 2=v
        #pragma unroll
        for (int mi = 0; mi < 4; ++mi) {
            const int gm = mBase + wm * 64 + mi * 16 + quad * 4;  // + r
            const int bb = gm >> 11;
            const int s0 = gm & 2047;
            #pragma unroll
            for (int ni = 0; ni < 4; ++ni) {
                const int gn = nBase + wn * 64 + ni * 16 + ml;
                const int c  = gn - which * Cq;
                const int hh = c >> 6;
                const int dd = c & 63;
                if (which < 2) {
                    #pragma unroll
                    for (int r = 0; r < 4; ++r) {
                        float val = acc[mi][ni][r];
                        float pv  = __shfl_xor(val, 1, 64);   // d-pair partner
                        const int fi = (s0 + r) * 32 + (dd >> 1);
                        float c0 = ctab[fi], sn = stab[fi];
                        float o = (dd & 1) ? (val * c0 + pv * sn)
                                           : (val * c0 - pv * sn);
                        unsigned short h0, l0;
                        if (which == 0) {
                            o *= 0.125f;                      // fold 64^-0.5
                            h0 = bfbits(o); l0 = lobits(o, h0);
                            const size_t ob =
                                ((size_t)(bb * Hq + hh) * Sq + s0 + r) * 128 + dd;
                            qp[ob]      = h0;
                            qp[ob + 64] = l0;
                        } else {
                            h0 = bfbits(o); l0 = lobits(o, h0);
                            // attn K blocked image
                            const int ss = s0 + r, rr = ss & 63, kt2 = ss >> 6;
                            const size_t pb =
                                ((size_t)(bb * Hq + hh) * 32 + kt2) * 8192
                                + (rr >> 2) * 512 + (rr & 3) * 128;
                            const int pch = (dd >> 3) ^ (rr & 15);
                            const int pcl = (8 + (dd >> 3)) ^ (rr & 15);
                            kp[pb + pch * 8 + (dd & 7)] = h0;
                            kp[pb + pcl * 8 + (dd & 7)] = l0;
                        }
                    }
                } else {
                    // attn V blocked image: row = d, chunks over keys
                    unsigned short hv[4], lv[4];
                    #pragma unroll
                    for (int r = 0; r < 4; ++r) {
                        float o = acc[mi][ni][r];
                        hv[r] = bfbits(o);
                        lv[r] = lobits(o, hv[r]);
                    }
                    const int kt2 = s0 >> 6;
                    const int keypart = (s0 & 63) >> 3;   // same for r=0..3
                    const size_t pb =
                        ((size_t)(bb * Hq + hh) * 32 + kt2) * 8192
                        + (dd >> 2) * 512 + (dd & 3) * 128;
                    const int pch = keypart ^ (dd & 15);
                    const int pcl = (8 + keypart) ^ (dd & 15);
                    *(ushort4*)&vp[pb + pch * 8 + (s0 & 7)] = *(ushort4*)hv;
                    *(ushort4*)&vp[pb + pcl * 8 + (s0 & 7)] = *(ushort4*)lv;
                }
            }
        }
    } else {
        #pragma unroll
        for (int mi = 0; mi < 4; ++mi) {
            const int gm = mBase + wm * 64 + mi * 16 + quad * 4;
            #pragma unroll
            for (int ni = 0; ni < 4; ++ni) {
                const int gn = nBase + wn * 64 + ni * 16 + ml;
                const float bz = bias[gn];
                #pragma unroll
                for (int r = 0; r < 4; ++r)
                    out0[(size_t)(gm + r) * Cq + gn] = acc[mi][ni][r] + bz;
            }
        }
    }
}

// ---------------------------------------------------------------------------
// Kernel 2: MFMA flash attention, bf16 3-term split, DOUBLE-BUFFERED tiles.
// Grid 768 = 32 qt x 24 bh (XCD = bh%8). Per iteration: ONE barrier ->
// issue DMA for tile kt+1 into buf^1 -> compute tile kt from buf. The
// compiler's vmcnt(0)-before-barrier then waits on a DMA issued one full
// compute phase earlier -> global latency off the critical path.
// LDS 73 KB -> 2 blocks/CU.
// ---------------------------------------------------------------------------
__global__ __launch_bounds__(256, 2) void attn_mfma_kernel(
    const unsigned short* __restrict__ qp, const unsigned short* __restrict__ kp,
    const unsigned short* __restrict__ vp, unsigned short* __restrict__ attns)
{
    __shared__ unsigned short k_s[2][64 * 128];   // rows=key, [hi64|lo64] swz
    __shared__ unsigned short v_s[2][64 * 128];   // rows=d,   [hi64|lo64] swz
    __shared__ unsigned int   pbuf[4][16][36];

    const int t    = threadIdx.x;
    const int w    = t >> 6;
    const int lane = t & 63;
    const int ml   = lane & 15;
    const int quad = lane >> 4;
    const int bi   = blockIdx.x;
    const int bh   = bi % 24;               // XCD = bh % 8
    const int qt   = bi / 24;               // 0..31

    // staging: waves 0,1 -> K; waves 2,3 -> V; wl picks 8KB half
    const bool isV = (w >= 2);
    const unsigned short* gsrc = isV ? vp : kp;
    const int wl = w & 1;
    const int Jb = wl * 8;
    const size_t gb = (size_t)bh * 262144;  // 32 blocks x 8192 shorts

    // ---- prologue: DMA tile 0 into buffer 0 ----
    {
        unsigned short* sd = isV ? v_s[0] : k_s[0];
        #pragma unroll
        for (int j = 0; j < 8; ++j)
            gld_lds16(gsrc + gb + (Jb + j) * 512 + lane * 8, sd + (Jb + j) * 512);
    }

    // ---- Q fragments (A-layout), paired rows [hi64|lo64] ----
    const size_t qrow = ((size_t)bh * Sq + qt * 64 + w * 16 + ml) * 128;
    bfv8 aQh[2], aQl[2];
    #pragma unroll
    for (int ks = 0; ks < 2; ++ks) {
        aQh[ks] = *(const bfv8*)(qp + qrow + ks * 32 + quad * 8);
        aQl[ks] = *(const bfv8*)(qp + qrow + 64 + ks * 32 + quad * 8);
    }

    float m_st[4], l_st[4];
    f32x4 O[4];
    #pragma unroll
    for (int r = 0; r < 4; ++r) { m_st[r] = -INFINITY; l_st[r] = 0.f; }
    #pragma unroll
    for (int ng = 0; ng < 4; ++ng) O[ng] = (f32x4){0.f, 0.f, 0.f, 0.f};

    for (int kt = 0; kt < 32; ++kt) {
        __syncthreads();   // drains each wave's DMA for buf[kt&1]; tile ready
        if (kt + 1 < 32) { // prefetch next tile into the other buffer
            unsigned short* sd = isV ? v_s[(kt + 1) & 1] : k_s[(kt + 1) & 1];
            const unsigned short* gt = gsrc + gb + (size_t)(kt + 1) * 8192;
            #pragma unroll
            for (int j = 0; j < 8; ++j)
                gld_lds16(gt + (Jb + j) * 512 + lane * 8, sd + (Jb + j) * 512);
        }
        const unsigned short* kc = k_s[kt & 1];
        const unsigned short* vc = v_s[kt & 1];

        // ---- scores S = Q K^T (scale pre-folded into q) ----
        f32x4 S[4];
        #pragma unroll
        for (int ng = 0; ng < 4; ++ng) {
            f32x4 acc = (f32x4){0.f, 0.f, 0.f, 0.f};
            #pragma unroll
            for (int ks = 0; ks < 2; ++ks) {
                const int rr = ng * 16 + ml;
                const int lcH = ks * 4 + quad;
                bfv8 bKh = *(const bfv8*)&kc[rr * 128 + ((lcH ^ (rr & 15)) << 3)];
                bfv8 bKl = *(const bfv8*)&kc[rr * 128 + (((8 + lcH) ^ (rr & 15)) << 3)];
                acc = MFMA16(aQh[ks], bKh, acc);
                acc = MFMA16(aQl[ks], bKh, acc);
                acc = MFMA16(aQh[ks], bKl, acc);
            }
            S[ng] = acc;
        }

        // ---- online softmax state update (DPP reductions) ----
        float nm[4], alpha[4];
        #pragma unroll
        for (int r = 0; r < 4; ++r) {
            float mx = fmaxf(fmaxf(S[0][r], S[1][r]), fmaxf(S[2][r], S[3][r]));
            mx = redmax16(mx);
            nm[r] = fmaxf(m_st[r], mx);
            alpha[r] = __expf(m_st[r] - nm[r]);
            m_st[r] = nm[r];
            O[0][r] *= alpha[r]; O[1][r] *= alpha[r];
            O[2][r] *= alpha[r]; O[3][r] *= alpha[r];
        }

        // ---- two key-half passes: exp -> pbuf -> A-frag -> PV ----
        float ps[4] = {0.f, 0.f, 0.f, 0.f};
        #pragma unroll
        for (int ksP = 0; ksP < 2; ++ksP) {
            #pragma unroll
            for (int g2 = 0; g2 < 2; ++g2) {
                const int ng = ksP * 2 + g2;
                #pragma unroll
                for (int r = 0; r < 4; ++r) {
                    float p = __expf(S[ng][r] - nm[r]);
                    ps[r] += p;
                    unsigned short ph = bfbits(p);
                    unsigned short pl = lobits(p, ph);
                    pbuf[w][quad * 4 + r][g2 * 16 + ml] =
                        (unsigned int)ph | ((unsigned int)pl << 16);
                }
            }
            bfv8 aPh, aPl;
            {
                const unsigned int* src = &pbuf[w][ml][quad * 8];
                uint4 w0 = *(const uint4*)src;
                uint4 w1 = *(const uint4*)(src + 4);
                union { unsigned short s[8]; bfv8 v; } hu, lu;
                unsigned int arr8[8] = {w0.x, w0.y, w0.z, w0.w,
                                        w1.x, w1.y, w1.z, w1.w};
                #pragma unroll
                for (int j = 0; j < 8; ++j) {
                    hu.s[j] = (unsigned short)(arr8[j] & 0xffffu);
                    lu.s[j] = (unsigned short)(arr8[j] >> 16);
                }
                aPh = hu.v;
                aPl = lu.v;
            }
            #pragma unroll
            for (int ngd = 0; ngd < 4; ++ngd) {
                const int rr = ngd * 16 + ml;
                const int lcH = ksP * 4 + quad;
                bfv8 bVh = *(const bfv8*)&vc[rr * 128 + ((lcH ^ (rr & 15)) << 3)];
                bfv8 bVl = *(const bfv8*)&vc[rr * 128 + (((8 + lcH) ^ (rr & 15)) << 3)];
                O[ngd] = MFMA16(aPh, bVh, O[ngd]);
                O[ngd] = MFMA16(aPl, bVh, O[ngd]);
                O[ngd] = MFMA16(aPh, bVl, O[ngd]);
            }
        }
        #pragma unroll
        for (int r = 0; r < 4; ++r) {
            ps[r] = redsum16(ps[r]);
            l_st[r] = l_st[r] * alpha[r] + ps[r];
        }
    }

    // ---- epilogue: O /= l, write proj-GEMM panel-blocked hi/lo image ----
    const int bb = bh / Hq, hh = bh % Hq;
    #pragma unroll
    for (int r = 0; r < 4; ++r) {
        const float il = 1.0f / l_st[r];
        const int srow = qt * 64 + w * 16 + quad * 4 + r;
        const int m = bb * 2048 + srow;
        const int panel = m >> 7, r128 = m & 127;
        const size_t rbase = (size_t)panel * PANEL_SHORTS
                           + (r128 >> 3) * 512 + (r128 & 7) * 64;
        #pragma unroll
        for (int ng = 0; ng < 4; ++ng) {
            const int k = hh * 64 + ng * 16 + ml;
            float o = O[ng][r] * il;
            unsigned short h0 = bfbits(o);
            unsigned short l0 = lobits(o, h0);
            const int step = k >> 5;
            const int lch  = (k & 31) >> 3;
            const size_t sb = rbase + (size_t)step * 8192;
            attns[sb + ((lch ^ (r128 & 7)) << 3)       + (k & 7)] = h0;
            attns[sb + (((4 + lch) ^ (r128 & 7)) << 3) + (k & 7)] = l0;
        }
    }
}

// ---------------------------------------------------------------------------
extern "C" void kernel_launch(void* const* d_in, const int* in_sizes, int n_in,
                              void* d_out, int out_size, void* d_ws, size_t ws_size,
                              hipStream_t stream) {
    const float* x     = (const float*)d_in[0];
    const float* Wqkv  = (const float*)d_in[1];
    const float* Wproj = (const float*)d_in[2];
    const float* bproj = (const float*)d_in[3];
    float* out = (float*)d_out;

    char* p = (char*)d_ws;
    unsigned short* xs    = (unsigned short*)p; p += (size_t)PANELS_X  * PANEL_SHORTS * 2;
    unsigned short* wqs   = (unsigned short*)p; p += (size_t)PANELS_WQ * PANEL_SHORTS * 2;
    unsigned short* wps   = (unsigned short*)p; p += (size_t)PANELS_WP * PANEL_SHORTS * 2;
    unsigned short* qp    = (unsigned short*)p; p += (size_t)24 * 2048 * 128 * 2;
    unsigned short* kp    = (unsigned short*)p; p += (size_t)24 * 32 * 8192 * 2;
    unsigned short* vp    = (unsigned short*)p; p += (size_t)24 * 32 * 8192 * 2;
    unsigned short* attns = (unsigned short*)p; p += (size_t)PANELS_X * PANEL_SHORTS * 2;
    float* ctab = (float*)p; p += (size_t)Sq * 32 * 4;
    float* stab = (float*)p; p += (size_t)Sq * 32 * 4;
    // total ws ~73 MB

    freq_kernel<<<256, 256, 0, stream>>>(ctab, stab);
    split_kernel<<<(PANELS_X + PANELS_WQ + PANELS_WP) * 24576 / 256, 256, 0, stream>>>(
        x, Wqkv, Wproj, xs, wqs, wps);
    gemm_mfma_kernel<0><<<dim3(18, 32), 256, 0, stream>>>(
        xs, wqs, ctab, stab, qp, kp, vp, nullptr, nullptr);
    attn_mfma_kernel<<<dim3(32 * 24), 256, 0, stream>>>(qp, kp, vp, attns);
    gemm_mfma_kernel<1><<<dim3(6, 32), 256, 0, stream>>>(
        attns, wps, ctab, stab, nullptr, nullptr, nullptr, out, bproj);
}